// Round 12
// baseline (129.368 us; speedup 1.0000x reference)
//
#include <hip/hip_runtime.h>

#define NN 50000
#define NE 800000
#define NBKT 196      // dst>>8 buckets: 196*256 = 50176 >= NN
#define NBLK 256      // blocks in hist/scatter kernels
#define EPB (NE / NBLK)            // 3125 edges per block
#define MATN (NBKT * NBLK)         // 50176

using short8 = __attribute__((ext_vector_type(8))) short;
using f32x4  = __attribute__((ext_vector_type(4))) float;
union U4S8 { uint4 u; short8 v; };

// ---- bf16 helpers (RNE, f32 accumulate everywhere) ----
__device__ __forceinline__ float lof(unsigned v) { return __uint_as_float(v << 16); }
__device__ __forceinline__ float hif(unsigned v) { return __uint_as_float(v & 0xffff0000u); }
__device__ __forceinline__ unsigned bf16rne(float f) {
    unsigned u = __float_as_uint(f);
    return (u + 0x7fffu + ((u >> 16) & 1u)) >> 16;
}
__device__ __forceinline__ unsigned pack2(float a, float b) {
    return bf16rne(a) | (bf16rne(b) << 16);
}
// ---- fp8 e4m3: 4 f32 -> packed uint (bytes a0..a3) ----
__device__ __forceinline__ unsigned fp8pack4(float a0, float a1, float a2, float a3) {
    int w = __builtin_amdgcn_cvt_pk_fp8_f32(a0, a1, 0, false);
    w = __builtin_amdgcn_cvt_pk_fp8_f32(a2, a3, w, true);
    return (unsigned)w;
}

// ---------------- K1: per-block bucket histogram (+ weight bf16 pack) ----------------
// mat[bucket][block] (bucket-major): row b = 256 consecutive ints.
// W1T[n][k]: k = real channel. W2T[n][q]: q = PERMUTED position, ch(q) = (q&7)*16 + (q>>3)
__global__ __launch_bounds__(256) void binhist_k(const int* __restrict__ dst,
                                                 int* __restrict__ mat,
                                                 const float* __restrict__ W1,
                                                 const float* __restrict__ W2,
                                                 unsigned* __restrict__ W1T,
                                                 unsigned* __restrict__ W2T) {
    __shared__ int hist[NBKT];
    const int tid = threadIdx.x;
    for (int i = tid; i < NBKT; i += 256) hist[i] = 0;

    const int g = blockIdx.x * 256 + tid;
    if (g < 8192) {
        const int n = g >> 6, k2 = (g & 63) * 2;
        W1T[g] = pack2(W1[k2 * 128 + n], W1[(k2 + 1) * 128 + n]);
    } else if (g < 8192 + 3072) {
        const int u = g - 8192;
        const int n = u >> 6;
        const int q0 = (u & 63) * 2, q1 = q0 + 1;
        const int c0 = (q0 & 7) * 16 + (q0 >> 3);
        const int c1 = (q1 & 7) * 16 + (q1 >> 3);
        W2T[u] = (n < 40) ? pack2(W2[c0 * 40 + n], W2[c1 * 40 + n]) : 0u;
    }
    __syncthreads();

    const int base = blockIdx.x * EPB;
    for (int e = base + tid; e < base + EPB; e += 256)
        atomicAdd(&hist[dst[e] >> 8], 1);
    __syncthreads();
    for (int i = tid; i < NBKT; i += 256)
        mat[i * NBLK + blockIdx.x] = hist[i];
}

// ---------------- K2 (merged scan+scatter): each block replicates the bucket scan ----------------
// Block b: reads whole mat coalesced -> {bucket totals, partial sums over cols<b},
// scans totals in LDS -> cursors for its own column; block 0 emits bucketoff; scatters its chunk.
__global__ __launch_bounds__(256) void scanscatter_k(const int* __restrict__ src,
                                                     const int* __restrict__ dst,
                                                     const int* __restrict__ mat,
                                                     unsigned* __restrict__ binned,
                                                     int* __restrict__ bucketoff) {
    __shared__ int tot[NBKT];
    __shared__ int cur[NBKT];
    __shared__ int sc[256];
    const int tid = threadIdx.x;
    const int lane = tid & 63;
    const int w = tid >> 6;       // wave 0..3
    const int b = blockIdx.x;     // 0..255
    for (int i = w; i < NBKT; i += 4) {
        int t = 0, p = 0;
#pragma unroll
        for (int c = 0; c < 4; ++c) {
            const int col = c * 64 + lane;
            const int v = mat[i * NBLK + col];
            t += v;
            p += (col < b) ? v : 0;
        }
#pragma unroll
        for (int off = 32; off; off >>= 1) {
            t += __shfl_xor(t, off, 64);
            p += __shfl_xor(p, off, 64);
        }
        if (lane == 0) { tot[i] = t; cur[i] = p; }
    }
    __syncthreads();
    // exclusive scan of tot[NBKT]
    const int v = (tid < NBKT) ? tot[tid] : 0;
    sc[tid] = v;
    __syncthreads();
#pragma unroll
    for (int off = 1; off < 256; off <<= 1) {
        int u = (tid >= off) ? sc[tid - off] : 0;
        __syncthreads();
        sc[tid] += u;
        __syncthreads();
    }
    const int excl = sc[tid] - v;
    if (tid < NBKT) cur[tid] += excl;
    if (b == 0) {
        if (tid < NBKT) bucketoff[tid] = excl;
        if (tid == 0) bucketoff[NBKT] = NE;
    }
    __syncthreads();
    // scatter this block's edge chunk
    const int base = b * EPB;
    for (int e = base + tid; e < base + EPB; e += 256) {
        const int d = dst[e];
        const int p = atomicAdd(&cur[d >> 8], 1);
        binned[p] = ((unsigned)(d & 255) << 16) | (unsigned)src[e];
    }
}

// ---------------- K3 (merged): blocks 0..195 = per-bucket CSR; 196..451 = GEMM1 ----------------
// GEMM1 (MFMA): H1[50000] fp8, position p = (ch&15)*8 + (ch>>4), 128B rows.
__global__ __launch_bounds__(256) void csrgemm1_k(const unsigned* __restrict__ binned,
                                                  const int* __restrict__ bucketoff,
                                                  int* __restrict__ rowoff,
                                                  unsigned short* __restrict__ eid,
                                                  const float* __restrict__ x,
                                                  const unsigned* __restrict__ W1T,
                                                  uint2* __restrict__ H1) {
    __shared__ int cnt[256];
    __shared__ int off[256];
    const int tid = threadIdx.x;
    if (blockIdx.x < NBKT) {
        // ---- bucketcsr ----
        const int b = blockIdx.x;
        const int beg = bucketoff[b];
        const int end = bucketoff[b + 1];
        cnt[tid] = 0;
        __syncthreads();
        for (int i = beg + tid; i < end; i += 256)
            atomicAdd(&cnt[(binned[i] >> 16) & 255u], 1);
        __syncthreads();
        const int v = cnt[tid];
        off[tid] = v;
        __syncthreads();
#pragma unroll
        for (int o = 1; o < 256; o <<= 1) {
            int u = (tid >= o) ? off[tid - o] : 0;
            __syncthreads();
            off[tid] += u;
            __syncthreads();
        }
        const int excl = off[tid] - v;
        const int node = b * 256 + tid;
        if (node <= NN) rowoff[node] = beg + excl;
        cnt[tid] = excl;   // cursor
        __syncthreads();
        for (int i = beg + tid; i < end; i += 256) {
            const unsigned e = binned[i];
            const int p = atomicAdd(&cnt[(e >> 16) & 255u], 1);
            eid[beg + p] = (unsigned short)(e & 0xffffu);
        }
        return;
    }
    // ---- gemm1 ----
    const int lane = tid & 63;
    const int cl = lane & 15;
    const int kh = lane >> 4;   // 0..3
    const int gw = ((blockIdx.x - NBKT) * 256 + tid) >> 6;   // 0..1023

    short8 Bf[8][4];
#pragma unroll
    for (int c = 0; c < 8; ++c)
#pragma unroll
        for (int kc = 0; kc < 4; ++kc) {
            U4S8 tb;
            tb.u = *(const uint4*)(W1T + ((c * 16 + cl) * 128 + kc * 32 + kh * 8) / 2);
            Bf[c][kc] = tb.v;
        }

    for (int mt = gw; mt < 3125; mt += 1024) {
        const int r0 = mt * 16;
        const float* ap = x + (long)(r0 + cl) * 128 + kh * 8;
        f32x4 acc[8];
#pragma unroll
        for (int c = 0; c < 8; ++c) acc[c] = (f32x4){0.f, 0.f, 0.f, 0.f};
#pragma unroll
        for (int kc = 0; kc < 4; ++kc) {
            const float4 p0 = *(const float4*)(ap + kc * 32);
            const float4 p1 = *(const float4*)(ap + kc * 32 + 4);
            U4S8 af;
            af.u.x = pack2(p0.x, p0.y);
            af.u.y = pack2(p0.z, p0.w);
            af.u.z = pack2(p1.x, p1.y);
            af.u.w = pack2(p1.z, p1.w);
#pragma unroll
            for (int c = 0; c < 8; ++c)
                acc[c] = __builtin_amdgcn_mfma_f32_16x16x32_bf16(af.v, Bf[c][kc], acc[c], 0, 0, 0);
        }
#pragma unroll
        for (int j = 0; j < 4; ++j) {
            uint2 o;
            o.x = fp8pack4(acc[0][j], acc[1][j], acc[2][j], acc[3][j]);
            o.y = fp8pack4(acc[4][j], acc[5][j], acc[6][j], acc[7][j]);
            H1[(long)(r0 + kh * 4 + j) * 16 + cl] = o;
        }
    }
}

// ---------------- gather1 + bias + relu: h[n](bf16, position layout) ----------------
// one wave per node: 8 edge-slots x 8 lanes x uint4 (16 fp8 positions per lane)
__global__ __launch_bounds__(256) void gather1_k(const uint4* __restrict__ H1,
                                                 const int* __restrict__ rowoff,
                                                 const unsigned short* __restrict__ eid,
                                                 const float* __restrict__ b1,
                                                 uint4* __restrict__ h) {
    const int n = blockIdx.x * 4 + (threadIdx.x >> 6);
    const int lane = threadIdx.x & 63;
    const int g = lane >> 3;      // edge slot 0..7
    const int cl = lane & 7;      // uint4 column (16B of 128B row)
    const int beg = rowoff[n], end = rowoff[n + 1];
    float a[16];
#pragma unroll
    for (int i = 0; i < 16; ++i) a[i] = 0.f;

#define ACC16(v)                                                             \
    {                                                                        \
        auto t0 = __builtin_amdgcn_cvt_pk_f32_fp8((int)(v).x, false);        \
        auto t1 = __builtin_amdgcn_cvt_pk_f32_fp8((int)(v).x, true);         \
        auto t2 = __builtin_amdgcn_cvt_pk_f32_fp8((int)(v).y, false);        \
        auto t3 = __builtin_amdgcn_cvt_pk_f32_fp8((int)(v).y, true);         \
        auto t4 = __builtin_amdgcn_cvt_pk_f32_fp8((int)(v).z, false);        \
        auto t5 = __builtin_amdgcn_cvt_pk_f32_fp8((int)(v).z, true);         \
        auto t6 = __builtin_amdgcn_cvt_pk_f32_fp8((int)(v).w, false);        \
        auto t7 = __builtin_amdgcn_cvt_pk_f32_fp8((int)(v).w, true);         \
        a[0] += t0[0];  a[1] += t0[1];  a[2] += t1[0];  a[3] += t1[1];       \
        a[4] += t2[0];  a[5] += t2[1];  a[6] += t3[0];  a[7] += t3[1];       \
        a[8] += t4[0];  a[9] += t4[1];  a[10] += t5[0]; a[11] += t5[1];      \
        a[12] += t6[0]; a[13] += t6[1]; a[14] += t7[0]; a[15] += t7[1];      \
    }

    int k = beg;
    for (; k + 15 < end; k += 16) {
        const uint4 vA = H1[eid[k + g] * 8 + cl];
        const uint4 vB = H1[eid[k + 8 + g] * 8 + cl];
        ACC16(vA);
        ACC16(vB);
    }
    for (; k + 7 < end; k += 8) {
        const uint4 v = H1[eid[k + g] * 8 + cl];
        ACC16(v);
    }
    if (k + g < end) {
        const uint4 v = H1[eid[k + g] * 8 + cl];
        ACC16(v);
    }
#undef ACC16

#pragma unroll
    for (int i = 0; i < 16; ++i) {
        a[i] += __shfl_xor(a[i], 8, 64);
        a[i] += __shfl_xor(a[i], 16, 64);
        a[i] += __shfl_xor(a[i], 32, 64);
    }
    if (lane < 8) {   // position p = cl*16+i -> channel (i&7)*16 + 2*cl + (i>>3)
        float r[16];
#pragma unroll
        for (int i = 0; i < 16; ++i)
            r[i] = fmaxf(a[i] + b1[(i & 7) * 16 + cl * 2 + (i >> 3)], 0.f);
        uint4 o1, o2;
        o1.x = pack2(r[0], r[1]);  o1.y = pack2(r[2], r[3]);
        o1.z = pack2(r[4], r[5]);  o1.w = pack2(r[6], r[7]);
        o2.x = pack2(r[8], r[9]);  o2.y = pack2(r[10], r[11]);
        o2.z = pack2(r[12], r[13]); o2.w = pack2(r[14], r[15]);
        h[n * 16 + cl * 2] = o1;
        h[n * 16 + cl * 2 + 1] = o2;
    }
}

// ---------------- GEMM2 (MFMA): H2[50000, pad 64](bf16) = h(bf16, pos layout) @ W2T(pos k) ----------------
__global__ __launch_bounds__(256) void gemm2_k(const unsigned* __restrict__ h,
                                               const unsigned* __restrict__ W2T,
                                               unsigned short* __restrict__ H2) {
    const int lane = threadIdx.x & 63;
    const int cl = lane & 15;
    const int kh = lane >> 4;
    const int gw = (blockIdx.x * 256 + threadIdx.x) >> 6;   // 0..1023

    short8 Bf[3][4];
#pragma unroll
    for (int c = 0; c < 3; ++c)
#pragma unroll
        for (int kc = 0; kc < 4; ++kc) {
            U4S8 tb;
            tb.u = *(const uint4*)(W2T + ((c * 16 + cl) * 128 + kc * 32 + kh * 8) / 2);
            Bf[c][kc] = tb.v;
        }

    for (int mt = gw; mt < 3125; mt += 1024) {
        const int r0 = mt * 16;
        const unsigned* ap = h + (long)(r0 + cl) * 64 + kh * 4;
        f32x4 acc[3];
#pragma unroll
        for (int c = 0; c < 3; ++c) acc[c] = (f32x4){0.f, 0.f, 0.f, 0.f};
#pragma unroll
        for (int kc = 0; kc < 4; ++kc) {
            U4S8 af;
            af.u = *(const uint4*)(ap + kc * 16);
#pragma unroll
            for (int c = 0; c < 3; ++c)
                acc[c] = __builtin_amdgcn_mfma_f32_16x16x32_bf16(af.v, Bf[c][kc], acc[c], 0, 0, 0);
        }
        unsigned short* hp = H2 + (long)(r0 + kh * 4) * 64;
#pragma unroll
        for (int c = 0; c < 3; ++c) {
            const int col = c * 16 + cl;
            if (col < 40) {
#pragma unroll
                for (int j = 0; j < 4; ++j)
                    hp[j * 64 + col] = (unsigned short)bf16rne(acc[c][j]);
            }
        }
    }
}

// ---------------- gather2 + bias + log_softmax ----------------
// one wave per node: 12 edge-groups x 5 lanes x uint4 (8 ch per lane); lanes 60..63 idle
__global__ __launch_bounds__(256) void gather2_k(const uint4* __restrict__ H2,
                                                 const int* __restrict__ rowoff,
                                                 const unsigned short* __restrict__ eid,
                                                 const float* __restrict__ b2,
                                                 float* __restrict__ out) {
    const int n = blockIdx.x * 4 + (threadIdx.x >> 6);
    const int lane = threadIdx.x & 63;
    const int g = lane / 5;         // edge-group 0..11 (g==12 idle)
    const int c4 = lane - g * 5;    // uint4 column 0..4 (ch 8c4..8c4+7)
    const int beg = rowoff[n], end = rowoff[n + 1];
    float a0 = 0.f, a1 = 0.f, a2 = 0.f, a3 = 0.f, a4 = 0.f, a5 = 0.f, a6 = 0.f, a7 = 0.f;
    if (g < 12) {
        int k = beg + g;
        for (; k + 12 < end; k += 24) {
            const uint4 v0 = H2[eid[k] * 8 + c4];
            const uint4 v1 = H2[eid[k + 12] * 8 + c4];
            a0 += lof(v0.x) + lof(v1.x); a1 += hif(v0.x) + hif(v1.x);
            a2 += lof(v0.y) + lof(v1.y); a3 += hif(v0.y) + hif(v1.y);
            a4 += lof(v0.z) + lof(v1.z); a5 += hif(v0.z) + hif(v1.z);
            a6 += lof(v0.w) + lof(v1.w); a7 += hif(v0.w) + hif(v1.w);
        }
        if (k < end) {
            const uint4 v = H2[eid[k] * 8 + c4];
            a0 += lof(v.x); a1 += hif(v.x);
            a2 += lof(v.y); a3 += hif(v.y);
            a4 += lof(v.z); a5 += hif(v.z);
            a6 += lof(v.w); a7 += hif(v.w);
        }
    }
    // fold 12 groups -> lanes 0..4 (tree; pairs in one statement read pre-update
    // values — sequential folds double-count, see r9 bug)
#define FOLD1(A, D) A += __shfl(A, lane + (D), 64)
#define FOLD2(A) A += __shfl(A, lane + 5, 64) + __shfl(A, lane + 10, 64)
    FOLD1(a0, 30); FOLD1(a1, 30); FOLD1(a2, 30); FOLD1(a3, 30);
    FOLD1(a4, 30); FOLD1(a5, 30); FOLD1(a6, 30); FOLD1(a7, 30);
    FOLD1(a0, 15); FOLD1(a1, 15); FOLD1(a2, 15); FOLD1(a3, 15);
    FOLD1(a4, 15); FOLD1(a5, 15); FOLD1(a6, 15); FOLD1(a7, 15);
    FOLD2(a0); FOLD2(a1); FOLD2(a2); FOLD2(a3);
    FOLD2(a4); FOLD2(a5); FOLD2(a6); FOLD2(a7);
#undef FOLD1
#undef FOLD2

    const bool act = (lane < 5);
    float4 bA = {0.f, 0.f, 0.f, 0.f}, bB = {0.f, 0.f, 0.f, 0.f};
    if (act) {
        bA = ((const float4*)b2)[lane * 2];
        bB = ((const float4*)b2)[lane * 2 + 1];
    }
    const float v0 = a0 + bA.x, v1 = a1 + bA.y, v2 = a2 + bA.z, v3 = a3 + bA.w;
    const float v4 = a4 + bB.x, v5 = a5 + bB.y, v6 = a6 + bB.z, v7 = a7 + bB.w;
    float m = act ? fmaxf(fmaxf(fmaxf(v0, v1), fmaxf(v2, v3)),
                          fmaxf(fmaxf(v4, v5), fmaxf(v6, v7))) : -INFINITY;
#pragma unroll
    for (int off = 32; off; off >>= 1) m = fmaxf(m, __shfl_xor(m, off, 64));
    float e = act ? (expf(v0 - m) + expf(v1 - m) + expf(v2 - m) + expf(v3 - m) +
                     expf(v4 - m) + expf(v5 - m) + expf(v6 - m) + expf(v7 - m)) : 0.f;
#pragma unroll
    for (int off = 32; off; off >>= 1) e += __shfl_xor(e, off, 64);
    const float ls = logf(e);
    if (act) {
        float4 oA = {v0 - m - ls, v1 - m - ls, v2 - m - ls, v3 - m - ls};
        float4 oB = {v4 - m - ls, v5 - m - ls, v6 - m - ls, v7 - m - ls};
        float4* op = (float4*)(out + (long)n * 40 + lane * 8);
        op[0] = oA;
        op[1] = oB;
    }
}

extern "C" void kernel_launch(void* const* d_in, const int* in_sizes, int n_in,
                              void* d_out, int out_size, void* d_ws, size_t ws_size,
                              hipStream_t stream) {
    const float* x  = (const float*)d_in[0];
    const int*   ei = (const int*)d_in[1];   // [2, NE]: src then dst
    const float* W1 = (const float*)d_in[2];
    const float* b1 = (const float*)d_in[3];
    const float* W2 = (const float*)d_in[4];
    const float* b2 = (const float*)d_in[5];
    const int* src = ei;
    const int* dst = ei + NE;

    unsigned* H1   = (unsigned*)d_ws;                  // NN*32 (fp8 rows, 128B)
    unsigned* h    = H1 + (size_t)NN * 32;             // NN*64 (bf16x2, pos layout); binned aliases
    unsigned* H2   = h + (size_t)NN * 64;              // NN*32 (padded bf16x2)
    unsigned* W1T  = H2 + (size_t)NN * 32;             // 8192
    unsigned* W2T  = W1T + 8192;                       // 3072
    int* mat       = (int*)(W2T + 3072);               // MATN
    int* bucketoff = mat + MATN;                       // NBKT+1
    int* rowoff    = bucketoff + NBKT + 1;             // NN+1
    unsigned short* eid = (unsigned short*)(rowoff + NN + 1);  // NE ushort
    unsigned* binned = h;                              // NE uint (3.2MB <= 12.8MB of h)
    float* out     = (float*)d_out;

    binhist_k<<<NBLK, 256, 0, stream>>>(dst, mat, W1, W2, W1T, W2T);
    scanscatter_k<<<NBLK, 256, 0, stream>>>(src, dst, mat, binned, bucketoff);
    csrgemm1_k<<<NBKT + 256, 256, 0, stream>>>(binned, bucketoff, rowoff, eid,
                                               x, W1T, (uint2*)H1);
    gather1_k<<<12500, 256, 0, stream>>>((const uint4*)H1, rowoff, eid, b1, (uint4*)h);
    gemm2_k<<<256, 256, 0, stream>>>(h, W2T, (unsigned short*)H2);
    gather2_k<<<12500, 256, 0, stream>>>((const uint4*)H2, rowoff, eid, b2, out);
}

// Round 13
// 110.455 us; speedup vs baseline: 1.1712x; 1.1712x over previous
//
#include <hip/hip_runtime.h>

#define NN 50000
#define NE 800000
#define NBKT 196      // dst>>8 buckets: 196*256 = 50176 >= NN
#define NBLK 256      // blocks in hist/scatter kernels
#define EPB (NE / NBLK)            // 3125 edges per block
#define MATN (NBKT * NBLK)         // 50176

using short8 = __attribute__((ext_vector_type(8))) short;
using f32x4  = __attribute__((ext_vector_type(4))) float;
union U4S8 { uint4 u; short8 v; };

// ---- bf16 helpers (RNE, f32 accumulate everywhere) ----
__device__ __forceinline__ float lof(unsigned v) { return __uint_as_float(v << 16); }
__device__ __forceinline__ float hif(unsigned v) { return __uint_as_float(v & 0xffff0000u); }
__device__ __forceinline__ unsigned bf16rne(float f) {
    unsigned u = __float_as_uint(f);
    return (u + 0x7fffu + ((u >> 16) & 1u)) >> 16;
}
__device__ __forceinline__ unsigned pack2(float a, float b) {
    return bf16rne(a) | (bf16rne(b) << 16);
}
// ---- fp8 e4m3: 4 f32 -> packed uint (bytes a0..a3) ----
__device__ __forceinline__ unsigned fp8pack4(float a0, float a1, float a2, float a3) {
    int w = __builtin_amdgcn_cvt_pk_fp8_f32(a0, a1, 0, false);
    w = __builtin_amdgcn_cvt_pk_fp8_f32(a2, a3, w, true);
    return (unsigned)w;
}

// ---------------- K1: per-block bucket histogram (+ weight bf16 pack) ----------------
// mat[bucket][block] (bucket-major): row b = 256 consecutive ints.
// W1T[n][k]: k = real channel. W2T[n][q]: q = PERMUTED position, ch(q) = (q&7)*16 + (q>>3)
__global__ __launch_bounds__(256) void binhist_k(const int* __restrict__ dst,
                                                 int* __restrict__ mat,
                                                 const float* __restrict__ W1,
                                                 const float* __restrict__ W2,
                                                 unsigned* __restrict__ W1T,
                                                 unsigned* __restrict__ W2T) {
    __shared__ int hist[NBKT];
    const int tid = threadIdx.x;
    for (int i = tid; i < NBKT; i += 256) hist[i] = 0;

    const int g = blockIdx.x * 256 + tid;
    if (g < 8192) {
        const int n = g >> 6, k2 = (g & 63) * 2;
        W1T[g] = pack2(W1[k2 * 128 + n], W1[(k2 + 1) * 128 + n]);
    } else if (g < 8192 + 3072) {
        const int u = g - 8192;
        const int n = u >> 6;
        const int q0 = (u & 63) * 2, q1 = q0 + 1;
        const int c0 = (q0 & 7) * 16 + (q0 >> 3);
        const int c1 = (q1 & 7) * 16 + (q1 >> 3);
        W2T[u] = (n < 40) ? pack2(W2[c0 * 40 + n], W2[c1 * 40 + n]) : 0u;
    }
    __syncthreads();

    const int base = blockIdx.x * EPB;
    for (int e = base + tid; e < base + EPB; e += 256)
        atomicAdd(&hist[dst[e] >> 8], 1);
    __syncthreads();
    for (int i = tid; i < NBKT; i += 256)
        mat[i * NBLK + blockIdx.x] = hist[i];
}

// ---------------- K2: bucket totals (row sums of mat; coalesced) ----------------
__global__ __launch_bounds__(256) void reduce_k(const int* __restrict__ mat,
                                                int* __restrict__ blocksum) {
    int v = mat[blockIdx.x * NBLK + threadIdx.x];
#pragma unroll
    for (int off = 32; off; off >>= 1) v += __shfl_xor(v, off, 64);
    __shared__ int ws[4];
    if ((threadIdx.x & 63) == 0) ws[threadIdx.x >> 6] = v;
    __syncthreads();
    if (threadIdx.x == 0) blocksum[blockIdx.x] = ws[0] + ws[1] + ws[2] + ws[3];
}

// ---------------- K3: scan bucket totals + scan each row -> scanned mat, bucketoff ----------------
__global__ __launch_bounds__(256) void scanfin_k(int* __restrict__ mat,
                                                 const int* __restrict__ blocksum,
                                                 int* __restrict__ bucketoff) {
    __shared__ int bs[256];
    __shared__ int sm[256];
    const int t = threadIdx.x;
    const int b = blockIdx.x;
    const int mybs = (t < NBKT) ? blocksum[t] : 0;
    bs[t] = mybs;
    __syncthreads();
#pragma unroll
    for (int off = 1; off < 256; off <<= 1) {
        int u = (t >= off) ? bs[t - off] : 0;
        __syncthreads();
        bs[t] += u;
        __syncthreads();
    }
    if (b == 0) {   // emit bucket boundaries (exclusive scan)
        if (t < NBKT) bucketoff[t] = bs[t] - mybs;
        if (t == 0) bucketoff[NBKT] = NE;
    }
    const int boff = bs[b] - blocksum[b];   // exclusive prefix for this bucket

    const int v = mat[b * NBLK + t];
    sm[t] = v;
    __syncthreads();
#pragma unroll
    for (int off = 1; off < 256; off <<= 1) {
        int u = (t >= off) ? sm[t - off] : 0;
        __syncthreads();
        sm[t] += u;
        __syncthreads();
    }
    mat[b * NBLK + t] = boff + sm[t] - v;   // scanned cursor start
}

// ---------------- K4: scatter (dst,src) into bucket-ordered binned[] ----------------
__global__ __launch_bounds__(256) void scatter_k(const int* __restrict__ src,
                                                 const int* __restrict__ dst,
                                                 const int* __restrict__ mat,
                                                 unsigned* __restrict__ binned) {
    __shared__ int cur[NBKT];
    const int tid = threadIdx.x;
    for (int i = tid; i < NBKT; i += 256) cur[i] = mat[i * NBLK + blockIdx.x];
    __syncthreads();
    const int base = blockIdx.x * EPB;
    for (int e = base + tid; e < base + EPB; e += 256) {
        const int d = dst[e];
        const int p = atomicAdd(&cur[d >> 8], 1);
        binned[p] = ((unsigned)(d & 255) << 16) | (unsigned)src[e];
    }
}

// ---------------- K5 (merged): blocks 0..195 = per-bucket CSR; 196..451 = GEMM1 ----------------
// GEMM1 (MFMA): H1[50000] fp8, position p = (ch&15)*8 + (ch>>4), 128B rows.
__global__ __launch_bounds__(256) void csrgemm1_k(const unsigned* __restrict__ binned,
                                                  const int* __restrict__ bucketoff,
                                                  int* __restrict__ rowoff,
                                                  unsigned short* __restrict__ eid,
                                                  const float* __restrict__ x,
                                                  const unsigned* __restrict__ W1T,
                                                  uint2* __restrict__ H1) {
    __shared__ int cnt[256];
    __shared__ int off[256];
    const int tid = threadIdx.x;
    if (blockIdx.x < NBKT) {
        // ---- bucketcsr ----
        const int b = blockIdx.x;
        const int beg = bucketoff[b];
        const int end = bucketoff[b + 1];
        cnt[tid] = 0;
        __syncthreads();
        for (int i = beg + tid; i < end; i += 256)
            atomicAdd(&cnt[(binned[i] >> 16) & 255u], 1);
        __syncthreads();
        const int v = cnt[tid];
        off[tid] = v;
        __syncthreads();
#pragma unroll
        for (int o = 1; o < 256; o <<= 1) {
            int u = (tid >= o) ? off[tid - o] : 0;
            __syncthreads();
            off[tid] += u;
            __syncthreads();
        }
        const int excl = off[tid] - v;
        const int node = b * 256 + tid;
        if (node <= NN) rowoff[node] = beg + excl;
        cnt[tid] = excl;   // cursor
        __syncthreads();
        for (int i = beg + tid; i < end; i += 256) {
            const unsigned e = binned[i];
            const int p = atomicAdd(&cnt[(e >> 16) & 255u], 1);
            eid[beg + p] = (unsigned short)(e & 0xffffu);
        }
        return;
    }
    // ---- gemm1 ----
    const int lane = tid & 63;
    const int cl = lane & 15;
    const int kh = lane >> 4;   // 0..3
    const int gw = ((blockIdx.x - NBKT) * 256 + tid) >> 6;   // 0..1023

    short8 Bf[8][4];
#pragma unroll
    for (int c = 0; c < 8; ++c)
#pragma unroll
        for (int kc = 0; kc < 4; ++kc) {
            U4S8 tb;
            tb.u = *(const uint4*)(W1T + ((c * 16 + cl) * 128 + kc * 32 + kh * 8) / 2);
            Bf[c][kc] = tb.v;
        }

    for (int mt = gw; mt < 3125; mt += 1024) {
        const int r0 = mt * 16;
        const float* ap = x + (long)(r0 + cl) * 128 + kh * 8;
        f32x4 acc[8];
#pragma unroll
        for (int c = 0; c < 8; ++c) acc[c] = (f32x4){0.f, 0.f, 0.f, 0.f};
#pragma unroll
        for (int kc = 0; kc < 4; ++kc) {
            const float4 p0 = *(const float4*)(ap + kc * 32);
            const float4 p1 = *(const float4*)(ap + kc * 32 + 4);
            U4S8 af;
            af.u.x = pack2(p0.x, p0.y);
            af.u.y = pack2(p0.z, p0.w);
            af.u.z = pack2(p1.x, p1.y);
            af.u.w = pack2(p1.z, p1.w);
#pragma unroll
            for (int c = 0; c < 8; ++c)
                acc[c] = __builtin_amdgcn_mfma_f32_16x16x32_bf16(af.v, Bf[c][kc], acc[c], 0, 0, 0);
        }
#pragma unroll
        for (int j = 0; j < 4; ++j) {
            uint2 o;
            o.x = fp8pack4(acc[0][j], acc[1][j], acc[2][j], acc[3][j]);
            o.y = fp8pack4(acc[4][j], acc[5][j], acc[6][j], acc[7][j]);
            H1[(long)(r0 + kh * 4 + j) * 16 + cl] = o;
        }
    }
}

// ---------------- gather1 + bias + relu: h[n](bf16, position layout) ----------------
// one wave per node: 8 edge-slots x 8 lanes x uint4 (16 fp8 positions per lane)
__global__ __launch_bounds__(256) void gather1_k(const uint4* __restrict__ H1,
                                                 const int* __restrict__ rowoff,
                                                 const unsigned short* __restrict__ eid,
                                                 const float* __restrict__ b1,
                                                 uint4* __restrict__ h) {
    const int n = blockIdx.x * 4 + (threadIdx.x >> 6);
    const int lane = threadIdx.x & 63;
    const int g = lane >> 3;      // edge slot 0..7
    const int cl = lane & 7;      // uint4 column (16B of 128B row)
    const int beg = rowoff[n], end = rowoff[n + 1];
    float a[16];
#pragma unroll
    for (int i = 0; i < 16; ++i) a[i] = 0.f;

#define ACC16(v)                                                             \
    {                                                                        \
        auto t0 = __builtin_amdgcn_cvt_pk_f32_fp8((int)(v).x, false);        \
        auto t1 = __builtin_amdgcn_cvt_pk_f32_fp8((int)(v).x, true);         \
        auto t2 = __builtin_amdgcn_cvt_pk_f32_fp8((int)(v).y, false);        \
        auto t3 = __builtin_amdgcn_cvt_pk_f32_fp8((int)(v).y, true);         \
        auto t4 = __builtin_amdgcn_cvt_pk_f32_fp8((int)(v).z, false);        \
        auto t5 = __builtin_amdgcn_cvt_pk_f32_fp8((int)(v).z, true);         \
        auto t6 = __builtin_amdgcn_cvt_pk_f32_fp8((int)(v).w, false);        \
        auto t7 = __builtin_amdgcn_cvt_pk_f32_fp8((int)(v).w, true);         \
        a[0] += t0[0];  a[1] += t0[1];  a[2] += t1[0];  a[3] += t1[1];       \
        a[4] += t2[0];  a[5] += t2[1];  a[6] += t3[0];  a[7] += t3[1];       \
        a[8] += t4[0];  a[9] += t4[1];  a[10] += t5[0]; a[11] += t5[1];      \
        a[12] += t6[0]; a[13] += t6[1]; a[14] += t7[0]; a[15] += t7[1];      \
    }

    int k = beg;
    for (; k + 15 < end; k += 16) {
        const uint4 vA = H1[eid[k + g] * 8 + cl];
        const uint4 vB = H1[eid[k + 8 + g] * 8 + cl];
        ACC16(vA);
        ACC16(vB);
    }
    for (; k + 7 < end; k += 8) {
        const uint4 v = H1[eid[k + g] * 8 + cl];
        ACC16(v);
    }
    if (k + g < end) {
        const uint4 v = H1[eid[k + g] * 8 + cl];
        ACC16(v);
    }
#undef ACC16

#pragma unroll
    for (int i = 0; i < 16; ++i) {
        a[i] += __shfl_xor(a[i], 8, 64);
        a[i] += __shfl_xor(a[i], 16, 64);
        a[i] += __shfl_xor(a[i], 32, 64);
    }
    if (lane < 8) {   // position p = cl*16+i -> channel (i&7)*16 + 2*cl + (i>>3)
        float r[16];
#pragma unroll
        for (int i = 0; i < 16; ++i)
            r[i] = fmaxf(a[i] + b1[(i & 7) * 16 + cl * 2 + (i >> 3)], 0.f);
        uint4 o1, o2;
        o1.x = pack2(r[0], r[1]);  o1.y = pack2(r[2], r[3]);
        o1.z = pack2(r[4], r[5]);  o1.w = pack2(r[6], r[7]);
        o2.x = pack2(r[8], r[9]);  o2.y = pack2(r[10], r[11]);
        o2.z = pack2(r[12], r[13]); o2.w = pack2(r[14], r[15]);
        h[n * 16 + cl * 2] = o1;
        h[n * 16 + cl * 2 + 1] = o2;
    }
}

// ---------------- GEMM2 (MFMA): H2[50000, pad 64](bf16) = h(bf16, pos layout) @ W2T(pos k) ----------------
__global__ __launch_bounds__(256) void gemm2_k(const unsigned* __restrict__ h,
                                               const unsigned* __restrict__ W2T,
                                               unsigned short* __restrict__ H2) {
    const int lane = threadIdx.x & 63;
    const int cl = lane & 15;
    const int kh = lane >> 4;
    const int gw = (blockIdx.x * 256 + threadIdx.x) >> 6;   // 0..1023

    short8 Bf[3][4];
#pragma unroll
    for (int c = 0; c < 3; ++c)
#pragma unroll
        for (int kc = 0; kc < 4; ++kc) {
            U4S8 tb;
            tb.u = *(const uint4*)(W2T + ((c * 16 + cl) * 128 + kc * 32 + kh * 8) / 2);
            Bf[c][kc] = tb.v;
        }

    for (int mt = gw; mt < 3125; mt += 1024) {
        const int r0 = mt * 16;
        const unsigned* ap = h + (long)(r0 + cl) * 64 + kh * 4;
        f32x4 acc[3];
#pragma unroll
        for (int c = 0; c < 3; ++c) acc[c] = (f32x4){0.f, 0.f, 0.f, 0.f};
#pragma unroll
        for (int kc = 0; kc < 4; ++kc) {
            U4S8 af;
            af.u = *(const uint4*)(ap + kc * 16);
#pragma unroll
            for (int c = 0; c < 3; ++c)
                acc[c] = __builtin_amdgcn_mfma_f32_16x16x32_bf16(af.v, Bf[c][kc], acc[c], 0, 0, 0);
        }
        unsigned short* hp = H2 + (long)(r0 + kh * 4) * 64;
#pragma unroll
        for (int c = 0; c < 3; ++c) {
            const int col = c * 16 + cl;
            if (col < 40) {
#pragma unroll
                for (int j = 0; j < 4; ++j)
                    hp[j * 64 + col] = (unsigned short)bf16rne(acc[c][j]);
            }
        }
    }
}

// ---------------- gather2 + bias + log_softmax ----------------
// one wave per node: 12 edge-groups x 5 lanes x uint4 (8 ch per lane); lanes 60..63 idle
__global__ __launch_bounds__(256) void gather2_k(const uint4* __restrict__ H2,
                                                 const int* __restrict__ rowoff,
                                                 const unsigned short* __restrict__ eid,
                                                 const float* __restrict__ b2,
                                                 float* __restrict__ out) {
    const int n = blockIdx.x * 4 + (threadIdx.x >> 6);
    const int lane = threadIdx.x & 63;
    const int g = lane / 5;         // edge-group 0..11 (g==12 idle)
    const int c4 = lane - g * 5;    // uint4 column 0..4 (ch 8c4..8c4+7)
    const int beg = rowoff[n], end = rowoff[n + 1];
    float a0 = 0.f, a1 = 0.f, a2 = 0.f, a3 = 0.f, a4 = 0.f, a5 = 0.f, a6 = 0.f, a7 = 0.f;
    if (g < 12) {
        int k = beg + g;
        for (; k + 12 < end; k += 24) {
            const uint4 v0 = H2[eid[k] * 8 + c4];
            const uint4 v1 = H2[eid[k + 12] * 8 + c4];
            a0 += lof(v0.x) + lof(v1.x); a1 += hif(v0.x) + hif(v1.x);
            a2 += lof(v0.y) + lof(v1.y); a3 += hif(v0.y) + hif(v1.y);
            a4 += lof(v0.z) + lof(v1.z); a5 += hif(v0.z) + hif(v1.z);
            a6 += lof(v0.w) + lof(v1.w); a7 += hif(v0.w) + hif(v1.w);
        }
        if (k < end) {
            const uint4 v = H2[eid[k] * 8 + c4];
            a0 += lof(v.x); a1 += hif(v.x);
            a2 += lof(v.y); a3 += hif(v.y);
            a4 += lof(v.z); a5 += hif(v.z);
            a6 += lof(v.w); a7 += hif(v.w);
        }
    }
    // fold 12 groups -> lanes 0..4 (tree; pairs in one statement read pre-update
    // values — sequential folds double-count, see r9 bug)
#define FOLD1(A, D) A += __shfl(A, lane + (D), 64)
#define FOLD2(A) A += __shfl(A, lane + 5, 64) + __shfl(A, lane + 10, 64)
    FOLD1(a0, 30); FOLD1(a1, 30); FOLD1(a2, 30); FOLD1(a3, 30);
    FOLD1(a4, 30); FOLD1(a5, 30); FOLD1(a6, 30); FOLD1(a7, 30);
    FOLD1(a0, 15); FOLD1(a1, 15); FOLD1(a2, 15); FOLD1(a3, 15);
    FOLD1(a4, 15); FOLD1(a5, 15); FOLD1(a6, 15); FOLD1(a7, 15);
    FOLD2(a0); FOLD2(a1); FOLD2(a2); FOLD2(a3);
    FOLD2(a4); FOLD2(a5); FOLD2(a6); FOLD2(a7);
#undef FOLD1
#undef FOLD2

    const bool act = (lane < 5);
    float4 bA = {0.f, 0.f, 0.f, 0.f}, bB = {0.f, 0.f, 0.f, 0.f};
    if (act) {
        bA = ((const float4*)b2)[lane * 2];
        bB = ((const float4*)b2)[lane * 2 + 1];
    }
    const float v0 = a0 + bA.x, v1 = a1 + bA.y, v2 = a2 + bA.z, v3 = a3 + bA.w;
    const float v4 = a4 + bB.x, v5 = a5 + bB.y, v6 = a6 + bB.z, v7 = a7 + bB.w;
    float m = act ? fmaxf(fmaxf(fmaxf(v0, v1), fmaxf(v2, v3)),
                          fmaxf(fmaxf(v4, v5), fmaxf(v6, v7))) : -INFINITY;
#pragma unroll
    for (int off = 32; off; off >>= 1) m = fmaxf(m, __shfl_xor(m, off, 64));
    float e = act ? (expf(v0 - m) + expf(v1 - m) + expf(v2 - m) + expf(v3 - m) +
                     expf(v4 - m) + expf(v5 - m) + expf(v6 - m) + expf(v7 - m)) : 0.f;
#pragma unroll
    for (int off = 32; off; off >>= 1) e += __shfl_xor(e, off, 64);
    const float ls = logf(e);
    if (act) {
        float4 oA = {v0 - m - ls, v1 - m - ls, v2 - m - ls, v3 - m - ls};
        float4 oB = {v4 - m - ls, v5 - m - ls, v6 - m - ls, v7 - m - ls};
        float4* op = (float4*)(out + (long)n * 40 + lane * 8);
        op[0] = oA;
        op[1] = oB;
    }
}

extern "C" void kernel_launch(void* const* d_in, const int* in_sizes, int n_in,
                              void* d_out, int out_size, void* d_ws, size_t ws_size,
                              hipStream_t stream) {
    const float* x  = (const float*)d_in[0];
    const int*   ei = (const int*)d_in[1];   // [2, NE]: src then dst
    const float* W1 = (const float*)d_in[2];
    const float* b1 = (const float*)d_in[3];
    const float* W2 = (const float*)d_in[4];
    const float* b2 = (const float*)d_in[5];
    const int* src = ei;
    const int* dst = ei + NE;

    unsigned* H1   = (unsigned*)d_ws;                  // NN*32 (fp8 rows, 128B)
    unsigned* h    = H1 + (size_t)NN * 32;             // NN*64 (bf16x2, pos layout); binned aliases
    unsigned* H2   = h + (size_t)NN * 64;              // NN*32 (padded bf16x2)
    unsigned* W1T  = H2 + (size_t)NN * 32;             // 8192
    unsigned* W2T  = W1T + 8192;                       // 3072
    int* mat       = (int*)(W2T + 3072);               // MATN
    int* blocksum  = mat + MATN;                       // NBKT (pad to 256)
    int* bucketoff = blocksum + 256;                   // NBKT+1
    int* rowoff    = bucketoff + NBKT + 1;             // NN+1
    unsigned short* eid = (unsigned short*)(rowoff + NN + 1);  // NE ushort
    unsigned* binned = h;                              // NE uint (3.2MB <= 12.8MB of h)
    float* out     = (float*)d_out;

    binhist_k<<<NBLK, 256, 0, stream>>>(dst, mat, W1, W2, W1T, W2T);
    reduce_k<<<NBKT, 256, 0, stream>>>(mat, blocksum);
    scanfin_k<<<NBKT, 256, 0, stream>>>(mat, blocksum, bucketoff);
    scatter_k<<<NBLK, 256, 0, stream>>>(src, dst, mat, binned);
    csrgemm1_k<<<NBKT + 256, 256, 0, stream>>>(binned, bucketoff, rowoff, eid,
                                               x, W1T, (uint2*)H1);
    gather1_k<<<12500, 256, 0, stream>>>((const uint4*)H1, rowoff, eid, b1, (uint4*)h);
    gemm2_k<<<256, 256, 0, stream>>>(h, W2T, (unsigned short*)H2);
    gather2_k<<<12500, 256, 0, stream>>>((const uint4*)H2, rowoff, eid, b2, out);
}

// Round 14
// 103.692 us; speedup vs baseline: 1.2476x; 1.0652x over previous
//
#include <hip/hip_runtime.h>

#define NN 50000
#define NE 800000
#define NBKT 196      // dst>>8 buckets: 196*256 = 50176 >= NN
#define NBLK 256      // blocks in hist/scatter kernels
#define EPB (NE / NBLK)            // 3125 edges per block
#define MATN (NBKT * NBLK)         // 50176

using short8 = __attribute__((ext_vector_type(8))) short;
using f32x4  = __attribute__((ext_vector_type(4))) float;
union U4S8 { uint4 u; short8 v; };

// ---- bf16 helpers (RNE, f32 accumulate everywhere) ----
__device__ __forceinline__ float lof(unsigned v) { return __uint_as_float(v << 16); }
__device__ __forceinline__ float hif(unsigned v) { return __uint_as_float(v & 0xffff0000u); }
__device__ __forceinline__ unsigned bf16rne(float f) {
    unsigned u = __float_as_uint(f);
    return (u + 0x7fffu + ((u >> 16) & 1u)) >> 16;
}
__device__ __forceinline__ unsigned pack2(float a, float b) {
    return bf16rne(a) | (bf16rne(b) << 16);
}
// ---- fp8 e4m3: 4 f32 -> packed uint (bytes a0..a3) ----
__device__ __forceinline__ unsigned fp8pack4(float a0, float a1, float a2, float a3) {
    int w = __builtin_amdgcn_cvt_pk_fp8_f32(a0, a1, 0, false);
    w = __builtin_amdgcn_cvt_pk_fp8_f32(a2, a3, w, true);
    return (unsigned)w;
}

// ---------------- K1: per-block bucket histogram (+ weight bf16 pack) ----------------
// mat[bucket][block] (bucket-major): row b = 256 consecutive ints.
// W1T[n][k]: k = real channel. W2T[n][q]: q = PERMUTED position, ch(q) = (q&7)*16 + (q>>3)
__global__ __launch_bounds__(256) void binhist_k(const int* __restrict__ dst,
                                                 int* __restrict__ mat,
                                                 const float* __restrict__ W1,
                                                 const float* __restrict__ W2,
                                                 unsigned* __restrict__ W1T,
                                                 unsigned* __restrict__ W2T) {
    __shared__ int hist[NBKT];
    const int tid = threadIdx.x;
    for (int i = tid; i < NBKT; i += 256) hist[i] = 0;

    const int g = blockIdx.x * 256 + tid;
    if (g < 8192) {
        const int n = g >> 6, k2 = (g & 63) * 2;
        W1T[g] = pack2(W1[k2 * 128 + n], W1[(k2 + 1) * 128 + n]);
    } else if (g < 8192 + 3072) {
        const int u = g - 8192;
        const int n = u >> 6;
        const int q0 = (u & 63) * 2, q1 = q0 + 1;
        const int c0 = (q0 & 7) * 16 + (q0 >> 3);
        const int c1 = (q1 & 7) * 16 + (q1 >> 3);
        W2T[u] = (n < 40) ? pack2(W2[c0 * 40 + n], W2[c1 * 40 + n]) : 0u;
    }
    __syncthreads();

    const int base = blockIdx.x * EPB;
    for (int e = base + tid; e < base + EPB; e += 256)
        atomicAdd(&hist[dst[e] >> 8], 1);
    __syncthreads();
    for (int i = tid; i < NBKT; i += 256)
        mat[i * NBLK + blockIdx.x] = hist[i];
}

// ---------------- K2: bucket totals (row sums of mat; coalesced) ----------------
__global__ __launch_bounds__(256) void reduce_k(const int* __restrict__ mat,
                                                int* __restrict__ blocksum) {
    int v = mat[blockIdx.x * NBLK + threadIdx.x];
#pragma unroll
    for (int off = 32; off; off >>= 1) v += __shfl_xor(v, off, 64);
    __shared__ int ws[4];
    if ((threadIdx.x & 63) == 0) ws[threadIdx.x >> 6] = v;
    __syncthreads();
    if (threadIdx.x == 0) blocksum[blockIdx.x] = ws[0] + ws[1] + ws[2] + ws[3];
}

// ---------------- K3: scan bucket totals + scan each row -> scanned mat, bucketoff ----------------
__global__ __launch_bounds__(256) void scanfin_k(int* __restrict__ mat,
                                                 const int* __restrict__ blocksum,
                                                 int* __restrict__ bucketoff) {
    __shared__ int bs[256];
    __shared__ int sm[256];
    const int t = threadIdx.x;
    const int b = blockIdx.x;
    const int mybs = (t < NBKT) ? blocksum[t] : 0;
    bs[t] = mybs;
    __syncthreads();
#pragma unroll
    for (int off = 1; off < 256; off <<= 1) {
        int u = (t >= off) ? bs[t - off] : 0;
        __syncthreads();
        bs[t] += u;
        __syncthreads();
    }
    if (b == 0) {   // emit bucket boundaries (exclusive scan)
        if (t < NBKT) bucketoff[t] = bs[t] - mybs;
        if (t == 0) bucketoff[NBKT] = NE;
    }
    const int boff = bs[b] - blocksum[b];   // exclusive prefix for this bucket

    const int v = mat[b * NBLK + t];
    sm[t] = v;
    __syncthreads();
#pragma unroll
    for (int off = 1; off < 256; off <<= 1) {
        int u = (t >= off) ? sm[t - off] : 0;
        __syncthreads();
        sm[t] += u;
        __syncthreads();
    }
    mat[b * NBLK + t] = boff + sm[t] - v;   // scanned cursor start
}

// ---------------- K4: scatter (dst,src) into bucket-ordered binned[] ----------------
__global__ __launch_bounds__(256) void scatter_k(const int* __restrict__ src,
                                                 const int* __restrict__ dst,
                                                 const int* __restrict__ mat,
                                                 unsigned* __restrict__ binned) {
    __shared__ int cur[NBKT];
    const int tid = threadIdx.x;
    for (int i = tid; i < NBKT; i += 256) cur[i] = mat[i * NBLK + blockIdx.x];
    __syncthreads();
    const int base = blockIdx.x * EPB;
    for (int e = base + tid; e < base + EPB; e += 256) {
        const int d = dst[e];
        const int p = atomicAdd(&cur[d >> 8], 1);
        binned[p] = ((unsigned)(d & 255) << 16) | (unsigned)src[e];
    }
}

// ---------------- K5 (merged): blocks 0..195 = per-bucket CSR; 196..451 = GEMM1 ----------------
// GEMM1 (MFMA): H1[50000] fp8, position p = (ch&15)*8 + (ch>>4), 128B rows.
__global__ __launch_bounds__(256) void csrgemm1_k(const unsigned* __restrict__ binned,
                                                  const int* __restrict__ bucketoff,
                                                  int* __restrict__ rowoff,
                                                  unsigned short* __restrict__ eid,
                                                  const float* __restrict__ x,
                                                  const unsigned* __restrict__ W1T,
                                                  uint2* __restrict__ H1) {
    __shared__ int cnt[256];
    __shared__ int off[256];
    const int tid = threadIdx.x;
    if (blockIdx.x < NBKT) {
        // ---- bucketcsr ----
        const int b = blockIdx.x;
        const int beg = bucketoff[b];
        const int end = bucketoff[b + 1];
        cnt[tid] = 0;
        __syncthreads();
        for (int i = beg + tid; i < end; i += 256)
            atomicAdd(&cnt[(binned[i] >> 16) & 255u], 1);
        __syncthreads();
        const int v = cnt[tid];
        off[tid] = v;
        __syncthreads();
#pragma unroll
        for (int o = 1; o < 256; o <<= 1) {
            int u = (tid >= o) ? off[tid - o] : 0;
            __syncthreads();
            off[tid] += u;
            __syncthreads();
        }
        const int excl = off[tid] - v;
        const int node = b * 256 + tid;
        if (node <= NN) rowoff[node] = beg + excl;
        cnt[tid] = excl;   // cursor
        __syncthreads();
        for (int i = beg + tid; i < end; i += 256) {
            const unsigned e = binned[i];
            const int p = atomicAdd(&cnt[(e >> 16) & 255u], 1);
            eid[beg + p] = (unsigned short)(e & 0xffffu);
        }
        return;
    }
    // ---- gemm1 ----
    const int lane = tid & 63;
    const int cl = lane & 15;
    const int kh = lane >> 4;   // 0..3
    const int gw = ((blockIdx.x - NBKT) * 256 + tid) >> 6;   // 0..1023

    short8 Bf[8][4];
#pragma unroll
    for (int c = 0; c < 8; ++c)
#pragma unroll
        for (int kc = 0; kc < 4; ++kc) {
            U4S8 tb;
            tb.u = *(const uint4*)(W1T + ((c * 16 + cl) * 128 + kc * 32 + kh * 8) / 2);
            Bf[c][kc] = tb.v;
        }

    for (int mt = gw; mt < 3125; mt += 1024) {
        const int r0 = mt * 16;
        const float* ap = x + (long)(r0 + cl) * 128 + kh * 8;
        f32x4 acc[8];
#pragma unroll
        for (int c = 0; c < 8; ++c) acc[c] = (f32x4){0.f, 0.f, 0.f, 0.f};
#pragma unroll
        for (int kc = 0; kc < 4; ++kc) {
            const float4 p0 = *(const float4*)(ap + kc * 32);
            const float4 p1 = *(const float4*)(ap + kc * 32 + 4);
            U4S8 af;
            af.u.x = pack2(p0.x, p0.y);
            af.u.y = pack2(p0.z, p0.w);
            af.u.z = pack2(p1.x, p1.y);
            af.u.w = pack2(p1.z, p1.w);
#pragma unroll
            for (int c = 0; c < 8; ++c)
                acc[c] = __builtin_amdgcn_mfma_f32_16x16x32_bf16(af.v, Bf[c][kc], acc[c], 0, 0, 0);
        }
#pragma unroll
        for (int j = 0; j < 4; ++j) {
            uint2 o;
            o.x = fp8pack4(acc[0][j], acc[1][j], acc[2][j], acc[3][j]);
            o.y = fp8pack4(acc[4][j], acc[5][j], acc[6][j], acc[7][j]);
            H1[(long)(r0 + kh * 4 + j) * 16 + cl] = o;
        }
    }
}

// ---------------- gather1 + bias + relu: h[n](bf16, position layout) ----------------
// one wave per node: 8 edge-slots x 8 lanes x uint4 (16 fp8 positions per lane)
__global__ __launch_bounds__(256) void gather1_k(const uint4* __restrict__ H1,
                                                 const int* __restrict__ rowoff,
                                                 const unsigned short* __restrict__ eid,
                                                 const float* __restrict__ b1,
                                                 uint4* __restrict__ h) {
    const int n = blockIdx.x * 4 + (threadIdx.x >> 6);
    const int lane = threadIdx.x & 63;
    const int g = lane >> 3;      // edge slot 0..7
    const int cl = lane & 7;      // uint4 column (16B of 128B row)
    const int beg = rowoff[n], end = rowoff[n + 1];
    float a[16];
#pragma unroll
    for (int i = 0; i < 16; ++i) a[i] = 0.f;

#define ACC16(v)                                                             \
    {                                                                        \
        auto t0 = __builtin_amdgcn_cvt_pk_f32_fp8((int)(v).x, false);        \
        auto t1 = __builtin_amdgcn_cvt_pk_f32_fp8((int)(v).x, true);         \
        auto t2 = __builtin_amdgcn_cvt_pk_f32_fp8((int)(v).y, false);        \
        auto t3 = __builtin_amdgcn_cvt_pk_f32_fp8((int)(v).y, true);         \
        auto t4 = __builtin_amdgcn_cvt_pk_f32_fp8((int)(v).z, false);        \
        auto t5 = __builtin_amdgcn_cvt_pk_f32_fp8((int)(v).z, true);         \
        auto t6 = __builtin_amdgcn_cvt_pk_f32_fp8((int)(v).w, false);        \
        auto t7 = __builtin_amdgcn_cvt_pk_f32_fp8((int)(v).w, true);         \
        a[0] += t0[0];  a[1] += t0[1];  a[2] += t1[0];  a[3] += t1[1];       \
        a[4] += t2[0];  a[5] += t2[1];  a[6] += t3[0];  a[7] += t3[1];       \
        a[8] += t4[0];  a[9] += t4[1];  a[10] += t5[0]; a[11] += t5[1];      \
        a[12] += t6[0]; a[13] += t6[1]; a[14] += t7[0]; a[15] += t7[1];      \
    }

    int k = beg;
    for (; k + 15 < end; k += 16) {
        const uint4 vA = H1[eid[k + g] * 8 + cl];
        const uint4 vB = H1[eid[k + 8 + g] * 8 + cl];
        ACC16(vA);
        ACC16(vB);
    }
    for (; k + 7 < end; k += 8) {
        const uint4 v = H1[eid[k + g] * 8 + cl];
        ACC16(v);
    }
    if (k + g < end) {
        const uint4 v = H1[eid[k + g] * 8 + cl];
        ACC16(v);
    }
#undef ACC16

#pragma unroll
    for (int i = 0; i < 16; ++i) {
        a[i] += __shfl_xor(a[i], 8, 64);
        a[i] += __shfl_xor(a[i], 16, 64);
        a[i] += __shfl_xor(a[i], 32, 64);
    }
    if (lane < 8) {   // position p = cl*16+i -> channel (i&7)*16 + 2*cl + (i>>3)
        float r[16];
#pragma unroll
        for (int i = 0; i < 16; ++i)
            r[i] = fmaxf(a[i] + b1[(i & 7) * 16 + cl * 2 + (i >> 3)], 0.f);
        uint4 o1, o2;
        o1.x = pack2(r[0], r[1]);  o1.y = pack2(r[2], r[3]);
        o1.z = pack2(r[4], r[5]);  o1.w = pack2(r[6], r[7]);
        o2.x = pack2(r[8], r[9]);  o2.y = pack2(r[10], r[11]);
        o2.z = pack2(r[12], r[13]); o2.w = pack2(r[14], r[15]);
        h[n * 16 + cl * 2] = o1;
        h[n * 16 + cl * 2 + 1] = o2;
    }
}

// ---------------- GEMM2 (MFMA): H2[50000] fp8 pos layout, 64-B rows ----------------
// H2 byte p = cl*4 + c  <->  channel c*16 + cl  (c=3 pad; c=2,cl>=8 naturally 0 via W2T zero rows)
__global__ __launch_bounds__(256) void gemm2_k(const unsigned* __restrict__ h,
                                               const unsigned* __restrict__ W2T,
                                               unsigned* __restrict__ H2) {
    const int lane = threadIdx.x & 63;
    const int cl = lane & 15;
    const int kh = lane >> 4;
    const int gw = (blockIdx.x * 256 + threadIdx.x) >> 6;   // 0..1023

    short8 Bf[3][4];
#pragma unroll
    for (int c = 0; c < 3; ++c)
#pragma unroll
        for (int kc = 0; kc < 4; ++kc) {
            U4S8 tb;
            tb.u = *(const uint4*)(W2T + ((c * 16 + cl) * 128 + kc * 32 + kh * 8) / 2);
            Bf[c][kc] = tb.v;
        }

    for (int mt = gw; mt < 3125; mt += 1024) {
        const int r0 = mt * 16;
        const unsigned* ap = h + (long)(r0 + cl) * 64 + kh * 4;
        f32x4 acc[3];
#pragma unroll
        for (int c = 0; c < 3; ++c) acc[c] = (f32x4){0.f, 0.f, 0.f, 0.f};
#pragma unroll
        for (int kc = 0; kc < 4; ++kc) {
            U4S8 af;
            af.u = *(const uint4*)(ap + kc * 16);
#pragma unroll
            for (int c = 0; c < 3; ++c)
                acc[c] = __builtin_amdgcn_mfma_f32_16x16x32_bf16(af.v, Bf[c][kc], acc[c], 0, 0, 0);
        }
#pragma unroll
        for (int j = 0; j < 4; ++j)
            H2[(long)(r0 + kh * 4 + j) * 16 + cl] =
                fp8pack4(acc[0][j], acc[1][j], acc[2][j], 0.f);
    }
}

// ---------------- gather2 + bias + log_softmax (H2 fp8, 16 uints/row) ----------------
// one wave per node: 4 edge-groups x 16 lanes x uint (no idle lanes).
// Lane q's uint holds channels {q, q+16, q+32(valid q<8), q+48(pad)}.
__global__ __launch_bounds__(256) void gather2_k(const unsigned* __restrict__ H2,
                                                 const int* __restrict__ rowoff,
                                                 const unsigned short* __restrict__ eid,
                                                 const float* __restrict__ b2,
                                                 float* __restrict__ out) {
    const int n = blockIdx.x * 4 + (threadIdx.x >> 6);
    const int lane = threadIdx.x & 63;
    const int g = lane >> 4;      // edge group 0..3
    const int q = lane & 15;      // uint column = channel group
    const int beg = rowoff[n], end = rowoff[n + 1];
    float a0 = 0.f, a1 = 0.f, a2 = 0.f;

#define ACCQ(u)                                                              \
    {                                                                        \
        auto t0 = __builtin_amdgcn_cvt_pk_f32_fp8((int)(u), false);          \
        auto t1 = __builtin_amdgcn_cvt_pk_f32_fp8((int)(u), true);           \
        a0 += t0[0]; a1 += t0[1]; a2 += t1[0];                               \
    }

    int k = beg;
    for (; k + 7 < end; k += 8) {
        const unsigned uA = H2[eid[k + g] * 16 + q];
        const unsigned uB = H2[eid[k + 4 + g] * 16 + q];
        ACCQ(uA);
        ACCQ(uB);
    }
    for (; k + 3 < end; k += 4) {
        const unsigned u = H2[eid[k + g] * 16 + q];
        ACCQ(u);
    }
    if (k + g < end) {
        const unsigned u = H2[eid[k + g] * 16 + q];
        ACCQ(u);
    }
#undef ACCQ

    // fold 4 edge groups (xor keeps it within-column)
    a0 += __shfl_xor(a0, 16, 64); a0 += __shfl_xor(a0, 32, 64);
    a1 += __shfl_xor(a1, 16, 64); a1 += __shfl_xor(a1, 32, 64);
    a2 += __shfl_xor(a2, 16, 64); a2 += __shfl_xor(a2, 32, 64);

    const bool has2 = (q < 8);
    const float v0 = a0 + b2[q];
    const float v1 = a1 + b2[16 + q];
    const float v2 = has2 ? (a2 + b2[32 + q]) : -INFINITY;
    float m = fmaxf(fmaxf(v0, v1), v2);
#pragma unroll
    for (int off = 8; off; off >>= 1) m = fmaxf(m, __shfl_xor(m, off, 64));
    float e = expf(v0 - m) + expf(v1 - m) + (has2 ? expf(v2 - m) : 0.f);
#pragma unroll
    for (int off = 8; off; off >>= 1) e += __shfl_xor(e, off, 64);
    const float ls = logf(e);
    if (lane < 16) {
        float* op = out + (long)n * 40;
        op[q] = v0 - m - ls;
        op[16 + q] = v1 - m - ls;
        if (has2) op[32 + q] = v2 - m - ls;
    }
}

extern "C" void kernel_launch(void* const* d_in, const int* in_sizes, int n_in,
                              void* d_out, int out_size, void* d_ws, size_t ws_size,
                              hipStream_t stream) {
    const float* x  = (const float*)d_in[0];
    const int*   ei = (const int*)d_in[1];   // [2, NE]: src then dst
    const float* W1 = (const float*)d_in[2];
    const float* b1 = (const float*)d_in[3];
    const float* W2 = (const float*)d_in[4];
    const float* b2 = (const float*)d_in[5];
    const int* src = ei;
    const int* dst = ei + NE;

    unsigned* H1   = (unsigned*)d_ws;                  // NN*32 (fp8 rows, 128B)
    unsigned* h    = H1 + (size_t)NN * 32;             // NN*64 (bf16x2, pos layout); binned aliases
    unsigned* H2   = h + (size_t)NN * 64;              // NN*16 (fp8 pos rows, 64B)
    unsigned* W1T  = H2 + (size_t)NN * 16;             // 8192
    unsigned* W2T  = W1T + 8192;                       // 3072
    int* mat       = (int*)(W2T + 3072);               // MATN
    int* blocksum  = mat + MATN;                       // NBKT (pad to 256)
    int* bucketoff = blocksum + 256;                   // NBKT+1
    int* rowoff    = bucketoff + NBKT + 1;             // NN+1
    unsigned short* eid = (unsigned short*)(rowoff + NN + 1);  // NE ushort
    unsigned* binned = h;                              // NE uint (3.2MB <= 12.8MB of h)
    float* out     = (float*)d_out;

    binhist_k<<<NBLK, 256, 0, stream>>>(dst, mat, W1, W2, W1T, W2T);
    reduce_k<<<NBKT, 256, 0, stream>>>(mat, blocksum);
    scanfin_k<<<NBKT, 256, 0, stream>>>(mat, blocksum, bucketoff);
    scatter_k<<<NBLK, 256, 0, stream>>>(src, dst, mat, binned);
    csrgemm1_k<<<NBKT + 256, 256, 0, stream>>>(binned, bucketoff, rowoff, eid,
                                               x, W1T, (uint2*)H1);
    gather1_k<<<12500, 256, 0, stream>>>((const uint4*)H1, rowoff, eid, b1, (uint4*)h);
    gemm2_k<<<256, 256, 0, stream>>>(h, W2T, H2);
    gather2_k<<<12500, 256, 0, stream>>>(H2, rowoff, eid, b2, out);
}